// Round 15
// baseline (410.675 us; speedup 1.0000x reference)
//
#include <hip/hip_runtime.h>

#define EMB 64
#define CH 4096

// ---------------------------------------------------------------------------
// Round 15: embed restructure. r13/r14 evidence: conflicts (3.85M, constant)
// were the xs staging scatter, NOT hs; swizzle added address math and broke
// immediate-offset ds_reads; 16KB weight staging + 5 barriers bought nothing
// (weights are L1-resident and identical for every block).
//  - weights read directly from global (float4, 256B/wave/k, L1 hit)
//  - xs row-major [r][NF], coalesced conflict-free staging (bit-identical
//    prenorm); GEMM1 reads scalar-broadcast (4 banks -> free)
//  - hs padded float4 [c][17]: immediate-offset b128, balanced bank-starts
//  - LDS 22.3KB -> 7 blocks/CU; 4 barriers (was 9)
// Everything else unchanged from r14 (quarter-wave aggs, slotted CSR, dual
// layer-1 gemm).
// ---------------------------------------------------------------------------

static __device__ __forceinline__ unsigned short f2bf(float x) {
    union { float f; unsigned u; } v; v.f = x;
    unsigned r = v.u + 0x7fffu + ((v.u >> 16) & 1u);   // RNE
    return (unsigned short)(r >> 16);
}
static __device__ __forceinline__ float bflo(unsigned w) {
    union { unsigned u; float f; } v; v.u = w << 16; return v.f;
}
static __device__ __forceinline__ float bfhi(unsigned w) {
    union { unsigned u; float f; } v; v.u = w & 0xffff0000u; return v.f;
}

__global__ __launch_bounds__(256) void zero_int_kernel(int* __restrict__ p, int n) {
    int i = blockIdx.x * 256 + threadIdx.x;
    if (i < n) p[i] = 0;
}

// one block: exclusive-scan both count arrays in place (n<=512 each); data[n]=E
__global__ __launch_bounds__(256) void scan_buckets_kernel(
    int* __restrict__ bc, int nbc, int* __restrict__ bv, int nbv, int E)
{
    __shared__ int sc[256];
    int t = threadIdx.x;
    {
        int v0 = (2 * t < nbc) ? bc[2 * t] : 0;
        int v1 = (2 * t + 1 < nbc) ? bc[2 * t + 1] : 0;
        sc[t] = v0 + v1;
        __syncthreads();
        for (int off = 1; off < 256; off <<= 1) {
            int x = (t >= off) ? sc[t - off] : 0;
            __syncthreads();
            sc[t] += x;
            __syncthreads();
        }
        int ex = (t > 0) ? sc[t - 1] : 0;
        if (2 * t < nbc) bc[2 * t] = ex;
        if (2 * t + 1 < nbc) bc[2 * t + 1] = ex + v0;
        if (t == 0) bc[nbc] = E;
        __syncthreads();
    }
    {
        int v0 = (2 * t < nbv) ? bv[2 * t] : 0;
        int v1 = (2 * t + 1 < nbv) ? bv[2 * t + 1] : 0;
        sc[t] = v0 + v1;
        __syncthreads();
        for (int off = 1; off < 256; off <<= 1) {
            int x = (t >= off) ? sc[t - off] : 0;
            __syncthreads();
            sc[t] += x;
            __syncthreads();
        }
        int ex = (t > 0) ? sc[t - 1] : 0;
        if (2 * t < nbv) bv[2 * t] = ex;
        if (2 * t + 1 < nbv) bv[2 * t + 1] = ex + v0;
        if (t == 0) bv[nbv] = E;
    }
}

// Phase 1: per-chunk LDS binning into FIXED per-bucket slots (base=i*SLOT),
// global per-bucket cursors count occupancy. Packed u32 {local<<23 | other}.
__global__ __launch_bounds__(256) void bin_edges_kernel(
    const int* __restrict__ src, const int* __restrict__ dst, int E,
    int* __restrict__ gcur_c, int* __restrict__ gcur_v,
    unsigned* __restrict__ tmp_c, unsigned* __restrict__ tmp_v,
    int shc, int shv, int NBC, int NBV, int SLOTC, int SLOTV)
{
    __shared__ int hc[512], hv[512];
    int t = threadIdx.x;
    int base = blockIdx.x * CH;
    int n = min(CH, E - base);
    unsigned mc = (1u << shc) - 1u, mv = (1u << shv) - 1u;

    for (int i = t; i < NBC; i += 256) hc[i] = 0;
    for (int i = t; i < NBV; i += 256) hv[i] = 0;
    __syncthreads();

    int ss[16], dd[16];
#pragma unroll
    for (int q = 0; q < 16; ++q) {
        int li = t + q * 256;
        bool ok = li < n;
        ss[q] = ok ? src[base + li] : -1;
        dd[q] = ok ? dst[base + li] : -1;
        if (ok) {
            atomicAdd(&hc[ss[q] >> shc], 1);
            atomicAdd(&hv[dd[q] >> shv], 1);
        }
    }
    __syncthreads();

    for (int i = t; i < NBC; i += 256) {
        int c = hc[i];
        hc[i] = c ? (i * SLOTC + atomicAdd(&gcur_c[i], c)) : 0;
    }
    for (int i = t; i < NBV; i += 256) {
        int c = hv[i];
        hv[i] = c ? (i * SLOTV + atomicAdd(&gcur_v[i], c)) : 0;
    }
    __syncthreads();

#pragma unroll
    for (int q = 0; q < 16; ++q) {
        int li = t + q * 256;
        if (li < n) {
            unsigned s = (unsigned)ss[q], d = (unsigned)dd[q];
            int pc = atomicAdd(&hc[s >> shc], 1);
            tmp_c[pc] = ((s & mc) << 23) | d;
            int pv = atomicAdd(&hv[d >> shv], 1);
            tmp_v[pv] = ((d & mv) << 23) | s;
        }
    }
}

// Phase 2 (dual): wg-per-bucket; reads slotted tmp, writes packed rp/adj.
__global__ __launch_bounds__(256) void regroup2_dual_kernel(
    const unsigned* __restrict__ tmpA, const int* __restrict__ bbA,
    int* __restrict__ rpA, int* __restrict__ adjA, int nAn, int shA, int nbA, int slotA,
    const unsigned* __restrict__ tmpB, const int* __restrict__ bbB,
    int* __restrict__ rpB, int* __restrict__ adjB, int nBn, int shB, int nbB, int slotB, int E)
{
    __shared__ int cnt[512];
    __shared__ int offs[512];
    __shared__ int sc[256];
    const unsigned* tmp; const int* bb; int* rp; int* adj; int n_nodes, sh, nb, b, slot;
    if ((int)blockIdx.x < nbA) {
        tmp = tmpA; bb = bbA; rp = rpA; adj = adjA; n_nodes = nAn; sh = shA; nb = nbA; slot = slotA; b = blockIdx.x;
    } else {
        tmp = tmpB; bb = bbB; rp = rpB; adj = adjB; n_nodes = nBn; sh = shB; nb = nbB; slot = slotB; b = blockIdx.x - nbA;
    }
    int t = threadIdx.x;
    int node0 = b << sh;
    int node1 = min(node0 + (1 << sh), n_nodes);
    int nn = node1 - node0;
    for (int i = t; i < nn; i += 256) cnt[i] = 0;
    __syncthreads();
    int adjbase = bb[b];
    int cntb = bb[b + 1] - adjbase;
    int sbeg = b * slot;
    for (int e = sbeg + t; e < sbeg + cntb; e += 256)
        atomicAdd(&cnt[tmp[e] >> 23], 1);
    __syncthreads();
    int v0 = (2 * t < nn) ? cnt[2 * t] : 0;
    int v1 = (2 * t + 1 < nn) ? cnt[2 * t + 1] : 0;
    sc[t] = v0 + v1;
    __syncthreads();
    for (int off = 1; off < 256; off <<= 1) {
        int x = (t >= off) ? sc[t - off] : 0;
        __syncthreads();
        sc[t] += x;
        __syncthreads();
    }
    int ex = (t > 0) ? sc[t - 1] : 0;
    if (2 * t < nn) offs[2 * t] = ex;
    if (2 * t + 1 < nn) offs[2 * t + 1] = ex + v0;
    __syncthreads();
    for (int i = t; i < nn; i += 256) {
        rp[node0 + i] = adjbase + offs[i];
        cnt[i] = 0;
    }
    if (b == nb - 1 && t == 0) rp[n_nodes] = E;
    __syncthreads();
    for (int e = sbeg + t; e < sbeg + cntb; e += 256) {
        unsigned p = tmp[e];
        int d = (int)(p >> 23);
        int r = atomicAdd(&cnt[d], 1);
        adj[adjbase + offs[d] + r] = (int)(p & 0x7fffffu);
    }
}

// ---------------------------------------------------------------------------
// Fused node pipeline body. LDS: xs float[64*NF] row-major + hs float4[64*17]
// (padded transposed tile: hs[c*17 + rb] = rows 4rb..4rb+3 of column c).
// Weights/biases read directly from global (L1-resident, broadcast).
// 4 barriers total. Bit-identical arithmetic to previous rounds.
// ---------------------------------------------------------------------------
template <int NF>
__device__ __forceinline__ void embed_body(
    float* xs, float4* hs,
    const float* __restrict__ x, const float* __restrict__ shift, const float* __restrict__ scale,
    const float* __restrict__ w1, const float* __restrict__ b1,
    const float* __restrict__ w2, const float* __restrict__ b2,
    const float* __restrict__ wll, const float* __restrict__ wlr,
    unsigned short* __restrict__ tb, float* __restrict__ u, int n, int bid)
{
    int t = threadIdx.x;
    long row0 = (long)bid * 64;
    int nrow = (n - row0 < 64) ? (int)(n - row0) : 64;

    // stage x row-major with prenorm (coalesced, conflict-free)
    for (int i = t; i < 64 * NF; i += 256) {
        int r = i / NF, k = i - r * NF;
        float v = (r < nrow) ? x[row0 * NF + i] : 0.f;
        xs[i] = (v + shift[k]) * scale[k];
    }
    int rb = t >> 4;
    int r0 = rb * 4;
    int c0 = (t & 15) * 4;
    float4 b1v = *(const float4*)&b1[c0];
    float4 b2v = *(const float4*)&b2[c0];
    __syncthreads();

    float a[4][4];
    // ---- GEMM1: h = relu(xs @ W1 + b1) ; W1 from global ----
#pragma unroll
    for (int i = 0; i < 4; ++i)
#pragma unroll
        for (int j = 0; j < 4; ++j) a[i][j] = 0.f;
#pragma unroll
    for (int k = 0; k < NF; ++k) {
        float x0 = xs[(r0 + 0) * NF + k];
        float x1 = xs[(r0 + 1) * NF + k];
        float x2 = xs[(r0 + 2) * NF + k];
        float x3 = xs[(r0 + 3) * NF + k];
        float4 wv = *(const float4*)&w1[k * EMB + c0];
        float wa[4] = {wv.x, wv.y, wv.z, wv.w};
#pragma unroll
        for (int j = 0; j < 4; ++j) {
            a[0][j] = fmaf(x0, wa[j], a[0][j]);
            a[1][j] = fmaf(x1, wa[j], a[1][j]);
            a[2][j] = fmaf(x2, wa[j], a[2][j]);
            a[3][j] = fmaf(x3, wa[j], a[3][j]);
        }
    }
    // h -> hs (padded transposed, immediate-offset b128 stores)
    {
        float ba[4] = {b1v.x, b1v.y, b1v.z, b1v.w};
#pragma unroll
        for (int j = 0; j < 4; ++j) {
            float4 o;
            o.x = fmaxf(a[0][j] + ba[j], 0.f);
            o.y = fmaxf(a[1][j] + ba[j], 0.f);
            o.z = fmaxf(a[2][j] + ba[j], 0.f);
            o.w = fmaxf(a[3][j] + ba[j], 0.f);
            hs[(c0 + j) * 17 + rb] = o;
        }
    }
    __syncthreads();

    // ---- GEMM2: xhat = relu(h @ W2 + b2) ; W2 from global ----
#pragma unroll
    for (int i = 0; i < 4; ++i)
#pragma unroll
        for (int j = 0; j < 4; ++j) a[i][j] = 0.f;
#pragma unroll 8
    for (int k = 0; k < EMB; ++k) {
        float4 xv = hs[k * 17 + rb];
        float4 wv = *(const float4*)&w2[k * EMB + c0];
        float xa[4] = {xv.x, xv.y, xv.z, xv.w};
        float wa[4] = {wv.x, wv.y, wv.z, wv.w};
#pragma unroll
        for (int i = 0; i < 4; ++i)
#pragma unroll
            for (int j = 0; j < 4; ++j)
                a[i][j] = fmaf(xa[i], wa[j], a[i][j]);
    }
    __syncthreads();                    // all h reads complete
    {
        float ba[4] = {b2v.x, b2v.y, b2v.z, b2v.w};
#pragma unroll
        for (int j = 0; j < 4; ++j) {
            float4 o;
            o.x = fmaxf(a[0][j] + ba[j], 0.f);
            o.y = fmaxf(a[1][j] + ba[j], 0.f);
            o.z = fmaxf(a[2][j] + ba[j], 0.f);
            o.w = fmaxf(a[3][j] + ba[j], 0.f);
            hs[(c0 + j) * 17 + rb] = o;
        }
    }
    __syncthreads();                    // xhat visible

    // ---- GEMM3: tb = bf16(xhat @ Wll) ; Wll from global ----
#pragma unroll
    for (int i = 0; i < 4; ++i)
#pragma unroll
        for (int j = 0; j < 4; ++j) a[i][j] = 0.f;
#pragma unroll 8
    for (int k = 0; k < EMB; ++k) {
        float4 xv = hs[k * 17 + rb];
        float4 wv = *(const float4*)&wll[k * EMB + c0];
        float xa[4] = {xv.x, xv.y, xv.z, xv.w};
        float wa[4] = {wv.x, wv.y, wv.z, wv.w};
#pragma unroll
        for (int i = 0; i < 4; ++i)
#pragma unroll
            for (int j = 0; j < 4; ++j)
                a[i][j] = fmaf(xa[i], wa[j], a[i][j]);
    }
#pragma unroll
    for (int i = 0; i < 4; ++i) {
        long gr = row0 + r0 + i;
        if (gr < n) {
            ushort4 o;
            o.x = f2bf(a[i][0]); o.y = f2bf(a[i][1]);
            o.z = f2bf(a[i][2]); o.w = f2bf(a[i][3]);
            *(ushort4*)(tb + gr * EMB + c0) = o;
        }
    }

    // ---- GEMM4: u = xhat @ Wlr ; Wlr from global ----
#pragma unroll
    for (int i = 0; i < 4; ++i)
#pragma unroll
        for (int j = 0; j < 4; ++j) a[i][j] = 0.f;
#pragma unroll 8
    for (int k = 0; k < EMB; ++k) {
        float4 xv = hs[k * 17 + rb];
        float4 wv = *(const float4*)&wlr[k * EMB + c0];
        float xa[4] = {xv.x, xv.y, xv.z, xv.w};
        float wa[4] = {wv.x, wv.y, wv.z, wv.w};
#pragma unroll
        for (int i = 0; i < 4; ++i)
#pragma unroll
            for (int j = 0; j < 4; ++j)
                a[i][j] = fmaf(xa[i], wa[j], a[i][j]);
    }
#pragma unroll
    for (int i = 0; i < 4; ++i) {
        long gr = row0 + r0 + i;
        if (gr < n)
            *(float4*)&u[gr * EMB + c0] = make_float4(a[i][0], a[i][1], a[i][2], a[i][3]);
    }
}

template <int NFA, int NFB>
__global__ __launch_bounds__(256) void embed_dual_kernel(
    const float* xA, const float* shA, const float* scA,
    const float* w1A, const float* b1A, const float* w2A, const float* b2A,
    const float* wllA, const float* wlrA, unsigned short* tbA, float* uA, int nA,
    const float* xB, const float* shB, const float* scB,
    const float* w1B, const float* b1B, const float* w2B, const float* b2B,
    const float* wllB, const float* wlrB, unsigned short* tbB, float* uB, int nB,
    int split)
{
    __shared__ __align__(16) float xs[64 * (NFA > NFB ? NFA : NFB)];
    __shared__ float4 hs[64 * 17];
    if ((int)blockIdx.x < split)
        embed_body<NFA>(xs, hs, xA, shA, scA, w1A, b1A, w2A, b2A, wllA, wlrA, tbA, uA, nA, blockIdx.x);
    else
        embed_body<NFB>(xs, hs, xB, shB, scB, w1B, b1B, w2B, b2B, wllB, wlrB, tbB, uB, nB, blockIdx.x - split);
}

// Layer-1 GEMMs, both sides in one dispatch (A: bf16 out, B: f32 out).
// Same global-weight + padded-hs structure as embed.
__global__ __launch_bounds__(256) void gemm64_dual_kernel(
    const float* __restrict__ XA, int nA, const float* __restrict__ WA, unsigned short* __restrict__ CA,
    const float* __restrict__ XB, int nB, const float* __restrict__ WB, float* __restrict__ CB, int split)
{
    __shared__ float4 hs[64 * 17];

    const float* X; const float* W; int n; int bid; bool bf;
    if ((int)blockIdx.x < split) { X = XA; W = WA; n = nA; bid = blockIdx.x; bf = true; }
    else { X = XB; W = WB; n = nB; bid = blockIdx.x - split; bf = false; }

    int t = threadIdx.x;
    {
        // stage X tile transposed into hs: thread reads one float4 of a row
        int r = t >> 2;
        int q4 = (t & 3) * 4;            // float4 index within the row (0,4,8,12)
        long gr = (long)bid * 64 + r;
        const float4* sp = (const float4*)(X + gr * EMB) + (t & 3) * 4;
#pragma unroll
        for (int q = 0; q < 4; ++q) {
            float4 v = (gr < n) ? sp[q] : make_float4(0.f, 0.f, 0.f, 0.f);
            int c = q4 * 4 + q * 4;      // starting column of this float4
            // scatter 4 scalars into transposed padded tile
            ((float*)&hs[(c + 0) * 17])[r] = v.x;
            ((float*)&hs[(c + 1) * 17])[r] = v.y;
            ((float*)&hs[(c + 2) * 17])[r] = v.z;
            ((float*)&hs[(c + 3) * 17])[r] = v.w;
        }
    }
    __syncthreads();

    int rb = t >> 4;
    int r0 = rb * 4;
    int c0 = (t & 15) * 4;
    float acc[4][4] = {{0.f}};
#pragma unroll 8
    for (int k = 0; k < EMB; ++k) {
        float4 xv = hs[k * 17 + rb];
        float4 wv = *(const float4*)&W[k * EMB + c0];
        float xa[4] = {xv.x, xv.y, xv.z, xv.w};
        float wa[4] = {wv.x, wv.y, wv.z, wv.w};
#pragma unroll
        for (int i = 0; i < 4; ++i)
#pragma unroll
            for (int j = 0; j < 4; ++j)
                acc[i][j] = fmaf(xa[i], wa[j], acc[i][j]);
    }

#pragma unroll
    for (int i = 0; i < 4; ++i) {
        long gr = (long)bid * 64 + r0 + i;
        if (gr < n) {
            if (bf) {
                ushort4 o;
                o.x = f2bf(acc[i][0]); o.y = f2bf(acc[i][1]);
                o.z = f2bf(acc[i][2]); o.w = f2bf(acc[i][3]);
                *(ushort4*)(CA + gr * EMB + c0) = o;
            } else {
                *(float4*)(CB + gr * EMB + c0) =
                    make_float4(acc[i][0], acc[i][1], acc[i][2], acc[i][3]);
            }
        }
    }
}

// out[node] = relu(mean_nbr tb[nbr] + bias + out[node])  (RMW; out holds u)
// 16 nodes/block: quarter-wave (16 lanes) per node. lane = 8*g + p:
// slot g in [0,2), oct p in [0,8); lane loads uint4 = 16B = 8 bf16.
__global__ __launch_bounds__(256) void agg_rmw_kernel(
    const unsigned short* __restrict__ tbl, const int* __restrict__ rowptr,
    const int* __restrict__ adj, const float* __restrict__ bias,
    float* __restrict__ out, int n_dst)
{
    int t = threadIdx.x;
    int node = blockIdx.x * 16 + (t >> 4);
    if (node >= n_dst) return;
    int sub = t & 15;
    int p = sub & 7;       // feature oct: bf16 [8p, 8p+8)
    int g = sub >> 3;      // neighbor slot 0..1
    int beg = rowptr[node];
    int end = rowptr[node + 1];
    const uint4* tb = (const uint4*)tbl;   // row stride = 8 uint4 (128B)
    float a0 = 0.f, a1 = 0.f, a2 = 0.f, a3 = 0.f;
    float a4 = 0.f, a5 = 0.f, a6 = 0.f, a7 = 0.f;
    int e = beg + g;
    for (; e + 2 < end; e += 4) {
        int r0 = adj[e];
        int r1 = adj[e + 2];
        uint4 w0 = tb[(long)r0 * 8 + p];
        uint4 w1 = tb[(long)r1 * 8 + p];
        a0 += bflo(w0.x) + bflo(w1.x);
        a1 += bfhi(w0.x) + bfhi(w1.x);
        a2 += bflo(w0.y) + bflo(w1.y);
        a3 += bfhi(w0.y) + bfhi(w1.y);
        a4 += bflo(w0.z) + bflo(w1.z);
        a5 += bfhi(w0.z) + bfhi(w1.z);
        a6 += bflo(w0.w) + bflo(w1.w);
        a7 += bfhi(w0.w) + bfhi(w1.w);
    }
    if (e < end) {
        uint4 w0 = tb[(long)adj[e] * 8 + p];
        a0 += bflo(w0.x); a1 += bfhi(w0.x);
        a2 += bflo(w0.y); a3 += bfhi(w0.y);
        a4 += bflo(w0.z); a5 += bfhi(w0.z);
        a6 += bflo(w0.w); a7 += bfhi(w0.w);
    }
    a0 += __shfl_xor(a0, 8);
    a1 += __shfl_xor(a1, 8);
    a2 += __shfl_xor(a2, 8);
    a3 += __shfl_xor(a3, 8);
    a4 += __shfl_xor(a4, 8);
    a5 += __shfl_xor(a5, 8);
    a6 += __shfl_xor(a6, 8);
    a7 += __shfl_xor(a7, 8);
    if (g == 0) {
        int cnt = end - beg;
        float inv = 1.f / (float)(cnt > 0 ? cnt : 1);
        const float4* bp = (const float4*)bias + 2 * p;
        float4 bv0 = bp[0], bv1 = bp[1];
        float4* op = (float4*)(out + (long)node * EMB) + 2 * p;
        float4 ov0 = op[0], ov1 = op[1];
        float4 o0, o1;
        o0.x = fmaxf(a0 * inv + bv0.x + ov0.x, 0.f);
        o0.y = fmaxf(a1 * inv + bv0.y + ov0.y, 0.f);
        o0.z = fmaxf(a2 * inv + bv0.z + ov0.z, 0.f);
        o0.w = fmaxf(a3 * inv + bv0.w + ov0.w, 0.f);
        o1.x = fmaxf(a4 * inv + bv1.x + ov1.x, 0.f);
        o1.y = fmaxf(a5 * inv + bv1.y + ov1.y, 0.f);
        o1.z = fmaxf(a6 * inv + bv1.z + ov1.z, 0.f);
        o1.w = fmaxf(a7 * inv + bv1.w + ov1.w, 0.f);
        op[0] = o0;
        op[1] = o1;
    }
}

extern "C" void kernel_launch(void* const* d_in, const int* in_sizes, int n_in,
                              void* d_out, int out_size, void* d_ws, size_t ws_size,
                              hipStream_t stream) {
    const float* cons_x     = (const float*)d_in[0];
    const float* var_x      = (const float*)d_in[1];
    const int*   eidx       = (const int*)d_in[3];
    const float* cons_shift = (const float*)d_in[4];
    const float* cons_scale = (const float*)d_in[5];
    const float* cons_w1    = (const float*)d_in[6];
    const float* cons_b1    = (const float*)d_in[7];
    const float* cons_w2    = (const float*)d_in[8];
    const float* cons_b2    = (const float*)d_in[9];
    const float* var_shift  = (const float*)d_in[10];
    const float* var_scale  = (const float*)d_in[11];
    const float* var_w1     = (const float*)d_in[12];
    const float* var_b1     = (const float*)d_in[13];
    const float* var_w2     = (const float*)d_in[14];
    const float* var_b2     = (const float*)d_in[15];
    const float* ll_w       = (const float*)d_in[18];
    const float* ll_b       = (const float*)d_in[19];
    const float* lr_w       = (const float*)d_in[20];

    const int nC = in_sizes[0] / 5;
    const int nV = in_sizes[1] / 19;
    const int E  = in_sizes[3] / 2;
    const int* src = eidx;       // constraint ids
    const int* dst = eidx + E;   // variable ids

    int shc = 0; while ((nC >> shc) >= 512) ++shc;
    int shv = 0; while ((nV >> shv) >= 512) ++shv;
    const int NBC = (nC + (1 << shc) - 1) >> shc;
    const int NBV = (nV + (1 << shv) - 1) >> shv;

    char* w = (char*)d_ws;
    auto alloc = [&](size_t bytes) {
        char* p = w;
        w += (bytes + 255) & ~(size_t)255;
        return p;
    };
    float* x_c = (float*)alloc((size_t)nC * EMB * 4);   // u_c, then xhat_c
    float* x_v = (float*)alloc((size_t)nV * EMB * 4);   // u_v, then xhat_v
    float* t_c = (float*)alloc((size_t)nC * EMB * 4);   // aliases: slotted tmp_c, then bf16 tb_c
    float* t_v = (float*)alloc((size_t)nV * EMB * 4);
    unsigned* tmp_c = (unsigned*)t_c;
    unsigned* tmp_v = (unsigned*)t_v;
    unsigned short* tb_c = (unsigned short*)t_c;
    unsigned short* tb_v = (unsigned short*)t_v;
    int* rp_v  = (int*)alloc((size_t)(nV + 1) * 4);
    int* rp_c  = (int*)alloc((size_t)(nC + 1) * 4);
    int* adj_v = (int*)alloc((size_t)E * 4);
    int* adj_c = (int*)alloc((size_t)E * 4);
    int* bkt   = (int*)alloc(2048 * 4);
    int* gcur_c = bkt;            // counts, then exclusive bases (NBC+1)
    int* gcur_v = bkt + 1024;     // counts, then exclusive bases (NBV+1)

    // fixed per-bucket slots in tmp (2x mean, clamped to region capacity)
    auto slot_for = [&](int NB, size_t cap_ints) {
        long s = 2L * E / NB;
        s = (s + 255) & ~255L;
        if (s < 4096) s = 4096;
        long cap = (long)(cap_ints / NB) & ~255L;
        if (s > cap) s = cap;
        return (int)s;
    };
    const int SLOTC = slot_for(NBC, (size_t)nC * EMB);
    const int SLOTV = slot_for(NBV, (size_t)nV * EMB);

    auto llw = [&](int l, int d) { return ll_w + (size_t)(l * 2 + d) * EMB * EMB; };
    auto lrw = [&](int l, int d) { return lr_w + (size_t)(l * 2 + d) * EMB * EMB; };
    auto llb = [&](int l, int d) { return ll_b + (size_t)(l * 2 + d) * EMB; };

    // ---- CSR build (no histogram pass: fixed slots + post-scan) ----
    zero_int_kernel<<<8, 256, 0, stream>>>(bkt, 2048);
    bin_edges_kernel<<<(E + CH - 1) / CH, 256, 0, stream>>>(src, dst, E, gcur_c, gcur_v,
                                                            tmp_c, tmp_v, shc, shv, NBC, NBV,
                                                            SLOTC, SLOTV);
    scan_buckets_kernel<<<1, 256, 0, stream>>>(gcur_c, NBC, gcur_v, NBV, E);
    regroup2_dual_kernel<<<NBV + NBC, 256, 0, stream>>>(
        tmp_v, gcur_v, rp_v, adj_v, nV, shv, NBV, SLOTV,
        tmp_c, gcur_c, rp_c, adj_c, nC, shc, NBC, SLOTC, E);

    // ---- fused embed + layer-0 GEMMs, both sides in one dispatch ----
    int gc = (nC + 63) / 64, gv = (nV + 63) / 64;
    embed_dual_kernel<5, 19><<<gc + gv, 256, 0, stream>>>(
        cons_x, cons_shift, cons_scale, cons_w1, cons_b1, cons_w2, cons_b2,
        llw(0, 0), lrw(0, 1), tb_c, x_c, nC,
        var_x, var_shift, var_scale, var_w1, var_b1, var_w2, var_b2,
        llw(0, 1), lrw(0, 0), tb_v, x_v, nV,
        gc);

    // ---- layer-0 aggs (RMW u -> xhat), SEQUENTIAL (L2 working-set) ----
    int gv16 = (nV + 15) / 16, gc16 = (nC + 15) / 16;
    agg_rmw_kernel<<<gv16, 256, 0, stream>>>(tb_c, rp_v, adj_v, llb(0, 0), x_v, nV);
    agg_rmw_kernel<<<gc16, 256, 0, stream>>>(tb_v, rp_c, adj_c, llb(0, 1), x_c, nC);

    // ---- layer-1 GEMMs, one dispatch ----
    gemm64_dual_kernel<<<gc + gv, 256, 0, stream>>>(
        x_c, nC, llw(1, 0), tb_c,
        x_v, nV, lrw(1, 0), (float*)d_out, gc);

    // ---- final layer-1 var agg (RMW d_out) ----
    agg_rmw_kernel<<<gv16, 256, 0, stream>>>(tb_c, rp_v, adj_v, llb(1, 0), (float*)d_out, nV);
}

// Round 16
// 390.633 us; speedup vs baseline: 1.0513x; 1.0513x over previous
//
#include <hip/hip_runtime.h>

#define EMB 64
#define CH 4096

// ---------------------------------------------------------------------------
// Round 16: revert embed to the empirically-best r12 version (123us in r13:
// phase-union LDS staging {xs,w1s}/{w2}/{wll}/{wlr} + float4 immediate-offset
// GEMMs). r15's global-weight variant serialized 256B/wave/k of L1 reads
// against the FMA stream (157us, VALUBusy 64->48). Occupancy was pinned at
// ~39% across 22-34KB LDS variants -> LDS was never the limiter; staged
// weights + vector LDS reads win. Single change vs r14 (which keeps the
// quarter-wave aggs, slotted CSR, sequential aggs, r14 gemm64_dual).
// ---------------------------------------------------------------------------

static __device__ __forceinline__ unsigned short f2bf(float x) {
    union { float f; unsigned u; } v; v.f = x;
    unsigned r = v.u + 0x7fffu + ((v.u >> 16) & 1u);   // RNE
    return (unsigned short)(r >> 16);
}
static __device__ __forceinline__ float bflo(unsigned w) {
    union { unsigned u; float f; } v; v.u = w << 16; return v.f;
}
static __device__ __forceinline__ float bfhi(unsigned w) {
    union { unsigned u; float f; } v; v.u = w & 0xffff0000u; return v.f;
}

__global__ __launch_bounds__(256) void zero_int_kernel(int* __restrict__ p, int n) {
    int i = blockIdx.x * 256 + threadIdx.x;
    if (i < n) p[i] = 0;
}

// one block: exclusive-scan both count arrays in place (n<=512 each); data[n]=E
__global__ __launch_bounds__(256) void scan_buckets_kernel(
    int* __restrict__ bc, int nbc, int* __restrict__ bv, int nbv, int E)
{
    __shared__ int sc[256];
    int t = threadIdx.x;
    {
        int v0 = (2 * t < nbc) ? bc[2 * t] : 0;
        int v1 = (2 * t + 1 < nbc) ? bc[2 * t + 1] : 0;
        sc[t] = v0 + v1;
        __syncthreads();
        for (int off = 1; off < 256; off <<= 1) {
            int x = (t >= off) ? sc[t - off] : 0;
            __syncthreads();
            sc[t] += x;
            __syncthreads();
        }
        int ex = (t > 0) ? sc[t - 1] : 0;
        if (2 * t < nbc) bc[2 * t] = ex;
        if (2 * t + 1 < nbc) bc[2 * t + 1] = ex + v0;
        if (t == 0) bc[nbc] = E;
        __syncthreads();
    }
    {
        int v0 = (2 * t < nbv) ? bv[2 * t] : 0;
        int v1 = (2 * t + 1 < nbv) ? bv[2 * t + 1] : 0;
        sc[t] = v0 + v1;
        __syncthreads();
        for (int off = 1; off < 256; off <<= 1) {
            int x = (t >= off) ? sc[t - off] : 0;
            __syncthreads();
            sc[t] += x;
            __syncthreads();
        }
        int ex = (t > 0) ? sc[t - 1] : 0;
        if (2 * t < nbv) bv[2 * t] = ex;
        if (2 * t + 1 < nbv) bv[2 * t + 1] = ex + v0;
        if (t == 0) bv[nbv] = E;
    }
}

// Phase 1: per-chunk LDS binning into FIXED per-bucket slots (base=i*SLOT),
// global per-bucket cursors count occupancy. Packed u32 {local<<23 | other}.
__global__ __launch_bounds__(256) void bin_edges_kernel(
    const int* __restrict__ src, const int* __restrict__ dst, int E,
    int* __restrict__ gcur_c, int* __restrict__ gcur_v,
    unsigned* __restrict__ tmp_c, unsigned* __restrict__ tmp_v,
    int shc, int shv, int NBC, int NBV, int SLOTC, int SLOTV)
{
    __shared__ int hc[512], hv[512];
    int t = threadIdx.x;
    int base = blockIdx.x * CH;
    int n = min(CH, E - base);
    unsigned mc = (1u << shc) - 1u, mv = (1u << shv) - 1u;

    for (int i = t; i < NBC; i += 256) hc[i] = 0;
    for (int i = t; i < NBV; i += 256) hv[i] = 0;
    __syncthreads();

    int ss[16], dd[16];
#pragma unroll
    for (int q = 0; q < 16; ++q) {
        int li = t + q * 256;
        bool ok = li < n;
        ss[q] = ok ? src[base + li] : -1;
        dd[q] = ok ? dst[base + li] : -1;
        if (ok) {
            atomicAdd(&hc[ss[q] >> shc], 1);
            atomicAdd(&hv[dd[q] >> shv], 1);
        }
    }
    __syncthreads();

    for (int i = t; i < NBC; i += 256) {
        int c = hc[i];
        hc[i] = c ? (i * SLOTC + atomicAdd(&gcur_c[i], c)) : 0;
    }
    for (int i = t; i < NBV; i += 256) {
        int c = hv[i];
        hv[i] = c ? (i * SLOTV + atomicAdd(&gcur_v[i], c)) : 0;
    }
    __syncthreads();

#pragma unroll
    for (int q = 0; q < 16; ++q) {
        int li = t + q * 256;
        if (li < n) {
            unsigned s = (unsigned)ss[q], d = (unsigned)dd[q];
            int pc = atomicAdd(&hc[s >> shc], 1);
            tmp_c[pc] = ((s & mc) << 23) | d;
            int pv = atomicAdd(&hv[d >> shv], 1);
            tmp_v[pv] = ((d & mv) << 23) | s;
        }
    }
}

// Phase 2 (dual): wg-per-bucket; reads slotted tmp, writes packed rp/adj.
__global__ __launch_bounds__(256) void regroup2_dual_kernel(
    const unsigned* __restrict__ tmpA, const int* __restrict__ bbA,
    int* __restrict__ rpA, int* __restrict__ adjA, int nAn, int shA, int nbA, int slotA,
    const unsigned* __restrict__ tmpB, const int* __restrict__ bbB,
    int* __restrict__ rpB, int* __restrict__ adjB, int nBn, int shB, int nbB, int slotB, int E)
{
    __shared__ int cnt[512];
    __shared__ int offs[512];
    __shared__ int sc[256];
    const unsigned* tmp; const int* bb; int* rp; int* adj; int n_nodes, sh, nb, b, slot;
    if ((int)blockIdx.x < nbA) {
        tmp = tmpA; bb = bbA; rp = rpA; adj = adjA; n_nodes = nAn; sh = shA; nb = nbA; slot = slotA; b = blockIdx.x;
    } else {
        tmp = tmpB; bb = bbB; rp = rpB; adj = adjB; n_nodes = nBn; sh = shB; nb = nbB; slot = slotB; b = blockIdx.x - nbA;
    }
    int t = threadIdx.x;
    int node0 = b << sh;
    int node1 = min(node0 + (1 << sh), n_nodes);
    int nn = node1 - node0;
    for (int i = t; i < nn; i += 256) cnt[i] = 0;
    __syncthreads();
    int adjbase = bb[b];
    int cntb = bb[b + 1] - adjbase;
    int sbeg = b * slot;
    for (int e = sbeg + t; e < sbeg + cntb; e += 256)
        atomicAdd(&cnt[tmp[e] >> 23], 1);
    __syncthreads();
    int v0 = (2 * t < nn) ? cnt[2 * t] : 0;
    int v1 = (2 * t + 1 < nn) ? cnt[2 * t + 1] : 0;
    sc[t] = v0 + v1;
    __syncthreads();
    for (int off = 1; off < 256; off <<= 1) {
        int x = (t >= off) ? sc[t - off] : 0;
        __syncthreads();
        sc[t] += x;
        __syncthreads();
    }
    int ex = (t > 0) ? sc[t - 1] : 0;
    if (2 * t < nn) offs[2 * t] = ex;
    if (2 * t + 1 < nn) offs[2 * t + 1] = ex + v0;
    __syncthreads();
    for (int i = t; i < nn; i += 256) {
        rp[node0 + i] = adjbase + offs[i];
        cnt[i] = 0;
    }
    if (b == nb - 1 && t == 0) rp[n_nodes] = E;
    __syncthreads();
    for (int e = sbeg + t; e < sbeg + cntb; e += 256) {
        unsigned p = tmp[e];
        int d = (int)(p >> 23);
        int r = atomicAdd(&cnt[d], 1);
        adj[adjbase + offs[d] + r] = (int)(p & 0x7fffffu);
    }
}

// ---------------------------------------------------------------------------
// Fused node pipeline body (33.4KB LDS: hs[64*68] + un[4096]) — r12 version.
//   phase A (un = xs+w1s): GEMM1 h = relu(prenorm(x) @ W1 + b1)
//   phase B (un = w2):     GEMM2 xhat = relu(h @ W2 + b2)
//   phase C (un = wll):    GEMM3 tb = bf16(xhat @ Wll)
//   phase D (un = wlr):    GEMM4 u = xhat @ Wlr
// hs transposed [col][row] stride 68 (float4-aligned, immediate offsets).
// ---------------------------------------------------------------------------
template <int NF>
__device__ __forceinline__ void embed_body(
    float* hs, float* un,
    const float* __restrict__ x, const float* __restrict__ shift, const float* __restrict__ scale,
    const float* __restrict__ w1, const float* __restrict__ b1,
    const float* __restrict__ w2, const float* __restrict__ b2,
    const float* __restrict__ wll, const float* __restrict__ wlr,
    unsigned short* __restrict__ tb, float* __restrict__ u, int n, int bid)
{
    int t = threadIdx.x;
    long row0 = (long)bid * 64;
    int nrow = (n - row0 < 64) ? (int)(n - row0) : 64;

    float* xs  = un;             // [NF][68] (transposed, prenormed)
    float* w1s = un + NF * 68;   // [NF][64]

    for (int i = t; i < NF * EMB; i += 256) w1s[i] = w1[i];
    for (int i = t; i < 64 * NF; i += 256) {
        int r = i / NF, k = i - r * NF;
        float v = (r < nrow) ? x[row0 * NF + i] : 0.f;
        xs[k * 68 + r] = (v + shift[k]) * scale[k];
    }
    int r0 = (t >> 4) * 4;
    int c0 = (t & 15) * 4;
    float4 b1v = *(const float4*)&b1[c0];
    float4 b2v = *(const float4*)&b2[c0];
    __syncthreads();

    float a[4][4];
    // ---- GEMM1 ----
#pragma unroll
    for (int i = 0; i < 4; ++i)
#pragma unroll
        for (int j = 0; j < 4; ++j) a[i][j] = 0.f;
#pragma unroll
    for (int k = 0; k < NF; ++k) {
        float4 xv = *(const float4*)&xs[k * 68 + r0];
        float4 wv = *(const float4*)&w1s[k * EMB + c0];
        float xa[4] = {xv.x, xv.y, xv.z, xv.w};
        float wa[4] = {wv.x, wv.y, wv.z, wv.w};
#pragma unroll
        for (int i = 0; i < 4; ++i)
#pragma unroll
            for (int j = 0; j < 4; ++j)
                a[i][j] = fmaf(xa[i], wa[j], a[i][j]);
    }
    __syncthreads();                    // un (xs,w1s) reads complete
    {
        float ba[4] = {b1v.x, b1v.y, b1v.z, b1v.w};
#pragma unroll
        for (int j = 0; j < 4; ++j) {
            float4 o;
            o.x = fmaxf(a[0][j] + ba[j], 0.f);
            o.y = fmaxf(a[1][j] + ba[j], 0.f);
            o.z = fmaxf(a[2][j] + ba[j], 0.f);
            o.w = fmaxf(a[3][j] + ba[j], 0.f);
            *(float4*)&hs[(c0 + j) * 68 + r0] = o;
        }
    }
    {
        const float4* wg = (const float4*)w2;
        float4* wl = (float4*)un;
#pragma unroll
        for (int q = 0; q < 4; ++q) wl[t + q * 256] = wg[t + q * 256];
    }
    __syncthreads();

    // ---- GEMM2 ----
#pragma unroll
    for (int i = 0; i < 4; ++i)
#pragma unroll
        for (int j = 0; j < 4; ++j) a[i][j] = 0.f;
#pragma unroll 8
    for (int k = 0; k < EMB; ++k) {
        float4 xv = *(const float4*)&hs[k * 68 + r0];
        float4 wv = *(const float4*)&un[k * EMB + c0];
        float xa[4] = {xv.x, xv.y, xv.z, xv.w};
        float wa[4] = {wv.x, wv.y, wv.z, wv.w};
#pragma unroll
        for (int i = 0; i < 4; ++i)
#pragma unroll
            for (int j = 0; j < 4; ++j)
                a[i][j] = fmaf(xa[i], wa[j], a[i][j]);
    }
    __syncthreads();                    // hs (h) + un (w2) reads complete
    {
        float ba[4] = {b2v.x, b2v.y, b2v.z, b2v.w};
#pragma unroll
        for (int j = 0; j < 4; ++j) {
            float4 o;
            o.x = fmaxf(a[0][j] + ba[j], 0.f);
            o.y = fmaxf(a[1][j] + ba[j], 0.f);
            o.z = fmaxf(a[2][j] + ba[j], 0.f);
            o.w = fmaxf(a[3][j] + ba[j], 0.f);
            *(float4*)&hs[(c0 + j) * 68 + r0] = o;
        }
    }
    {
        const float4* wg = (const float4*)wll;
        float4* wl = (float4*)un;
#pragma unroll
        for (int q = 0; q < 4; ++q) wl[t + q * 256] = wg[t + q * 256];
    }
    __syncthreads();

    // ---- GEMM3: tb = bf16(xhat @ Wll) ----
#pragma unroll
    for (int i = 0; i < 4; ++i)
#pragma unroll
        for (int j = 0; j < 4; ++j) a[i][j] = 0.f;
#pragma unroll 8
    for (int k = 0; k < EMB; ++k) {
        float4 xv = *(const float4*)&hs[k * 68 + r0];
        float4 wv = *(const float4*)&un[k * EMB + c0];
        float xa[4] = {xv.x, xv.y, xv.z, xv.w};
        float wa[4] = {wv.x, wv.y, wv.z, wv.w};
#pragma unroll
        for (int i = 0; i < 4; ++i)
#pragma unroll
            for (int j = 0; j < 4; ++j)
                a[i][j] = fmaf(xa[i], wa[j], a[i][j]);
    }
    __syncthreads();                    // un (wll) reads complete
    {
        const float4* wg = (const float4*)wlr;
        float4* wl = (float4*)un;
#pragma unroll
        for (int q = 0; q < 4; ++q) wl[t + q * 256] = wg[t + q * 256];
    }
#pragma unroll
    for (int i = 0; i < 4; ++i) {
        long gr = row0 + r0 + i;
        if (gr < n) {
            ushort4 o;
            o.x = f2bf(a[i][0]); o.y = f2bf(a[i][1]);
            o.z = f2bf(a[i][2]); o.w = f2bf(a[i][3]);
            *(ushort4*)(tb + gr * EMB + c0) = o;
        }
    }
    __syncthreads();

    // ---- GEMM4: u = xhat @ Wlr ----
#pragma unroll
    for (int i = 0; i < 4; ++i)
#pragma unroll
        for (int j = 0; j < 4; ++j) a[i][j] = 0.f;
#pragma unroll 8
    for (int k = 0; k < EMB; ++k) {
        float4 xv = *(const float4*)&hs[k * 68 + r0];
        float4 wv = *(const float4*)&un[k * EMB + c0];
        float xa[4] = {xv.x, xv.y, xv.z, xv.w};
        float wa[4] = {wv.x, wv.y, wv.z, wv.w};
#pragma unroll
        for (int i = 0; i < 4; ++i)
#pragma unroll
            for (int j = 0; j < 4; ++j)
                a[i][j] = fmaf(xa[i], wa[j], a[i][j]);
    }
#pragma unroll
    for (int i = 0; i < 4; ++i) {
        long gr = row0 + r0 + i;
        if (gr < n)
            *(float4*)&u[gr * EMB + c0] = make_float4(a[i][0], a[i][1], a[i][2], a[i][3]);
    }
}

template <int NFA, int NFB>
__global__ __launch_bounds__(256) void embed_dual_kernel(
    const float* xA, const float* shA, const float* scA,
    const float* w1A, const float* b1A, const float* w2A, const float* b2A,
    const float* wllA, const float* wlrA, unsigned short* tbA, float* uA, int nA,
    const float* xB, const float* shB, const float* scB,
    const float* w1B, const float* b1B, const float* w2B, const float* b2B,
    const float* wllB, const float* wlrB, unsigned short* tbB, float* uB, int nB,
    int split)
{
    __shared__ __align__(16) float hs[EMB * 68];
    __shared__ __align__(16) float un[4096];
    if ((int)blockIdx.x < split)
        embed_body<NFA>(hs, un, xA, shA, scA, w1A, b1A, w2A, b2A, wllA, wlrA, tbA, uA, nA, blockIdx.x);
    else
        embed_body<NFB>(hs, un, xB, shB, scB, w1B, b1B, w2B, b2B, wllB, wlrB, tbB, uB, nB, blockIdx.x - split);
}

// Layer-1 GEMMs, both sides in one dispatch (A: bf16 out, B: f32 out).
// r14 structure: transposed padded float4 tile + weights from global.
__global__ __launch_bounds__(256) void gemm64_dual_kernel(
    const float* __restrict__ XA, int nA, const float* __restrict__ WA, unsigned short* __restrict__ CA,
    const float* __restrict__ XB, int nB, const float* __restrict__ WB, float* __restrict__ CB, int split)
{
    __shared__ float4 hs[64 * 17];

    const float* X; const float* W; int n; int bid; bool bf;
    if ((int)blockIdx.x < split) { X = XA; W = WA; n = nA; bid = blockIdx.x; bf = true; }
    else { X = XB; W = WB; n = nB; bid = blockIdx.x - split; bf = false; }

    int t = threadIdx.x;
    {
        int r = t >> 2;
        int q4 = (t & 3) * 4;
        long gr = (long)bid * 64 + r;
        const float4* sp = (const float4*)(X + gr * EMB) + (t & 3) * 4;
#pragma unroll
        for (int q = 0; q < 4; ++q) {
            float4 v = (gr < n) ? sp[q] : make_float4(0.f, 0.f, 0.f, 0.f);
            int c = q4 * 4 + q * 4;
            ((float*)&hs[(c + 0) * 17])[r] = v.x;
            ((float*)&hs[(c + 1) * 17])[r] = v.y;
            ((float*)&hs[(c + 2) * 17])[r] = v.z;
            ((float*)&hs[(c + 3) * 17])[r] = v.w;
        }
    }
    __syncthreads();

    int rb = t >> 4;
    int r0 = rb * 4;
    int c0 = (t & 15) * 4;
    float acc[4][4] = {{0.f}};
#pragma unroll 8
    for (int k = 0; k < EMB; ++k) {
        float4 xv = hs[k * 17 + rb];
        float4 wv = *(const float4*)&W[k * EMB + c0];
        float xa[4] = {xv.x, xv.y, xv.z, xv.w};
        float wa[4] = {wv.x, wv.y, wv.z, wv.w};
#pragma unroll
        for (int i = 0; i < 4; ++i)
#pragma unroll
            for (int j = 0; j < 4; ++j)
                acc[i][j] = fmaf(xa[i], wa[j], acc[i][j]);
    }

#pragma unroll
    for (int i = 0; i < 4; ++i) {
        long gr = (long)bid * 64 + r0 + i;
        if (gr < n) {
            if (bf) {
                ushort4 o;
                o.x = f2bf(acc[i][0]); o.y = f2bf(acc[i][1]);
                o.z = f2bf(acc[i][2]); o.w = f2bf(acc[i][3]);
                *(ushort4*)(CA + gr * EMB + c0) = o;
            } else {
                *(float4*)(CB + gr * EMB + c0) =
                    make_float4(acc[i][0], acc[i][1], acc[i][2], acc[i][3]);
            }
        }
    }
}

// out[node] = relu(mean_nbr tb[nbr] + bias + out[node])  (RMW; out holds u)
// 16 nodes/block: quarter-wave (16 lanes) per node. lane = 8*g + p:
// slot g in [0,2), oct p in [0,8); lane loads uint4 = 16B = 8 bf16.
__global__ __launch_bounds__(256) void agg_rmw_kernel(
    const unsigned short* __restrict__ tbl, const int* __restrict__ rowptr,
    const int* __restrict__ adj, const float* __restrict__ bias,
    float* __restrict__ out, int n_dst)
{
    int t = threadIdx.x;
    int node = blockIdx.x * 16 + (t >> 4);
    if (node >= n_dst) return;
    int sub = t & 15;
    int p = sub & 7;       // feature oct: bf16 [8p, 8p+8)
    int g = sub >> 3;      // neighbor slot 0..1
    int beg = rowptr[node];
    int end = rowptr[node + 1];
    const uint4* tb = (const uint4*)tbl;   // row stride = 8 uint4 (128B)
    float a0 = 0.f, a1 = 0.f, a2 = 0.f, a3 = 0.f;
    float a4 = 0.f, a5 = 0.f, a6 = 0.f, a7 = 0.f;
    int e = beg + g;
    for (; e + 2 < end; e += 4) {
        int r0 = adj[e];
        int r1 = adj[e + 2];
        uint4 w0 = tb[(long)r0 * 8 + p];
        uint4 w1 = tb[(long)r1 * 8 + p];
        a0 += bflo(w0.x) + bflo(w1.x);
        a1 += bfhi(w0.x) + bfhi(w1.x);
        a2 += bflo(w0.y) + bflo(w1.y);
        a3 += bfhi(w0.y) + bfhi(w1.y);
        a4 += bflo(w0.z) + bflo(w1.z);
        a5 += bfhi(w0.z) + bfhi(w1.z);
        a6 += bflo(w0.w) + bflo(w1.w);
        a7 += bfhi(w0.w) + bfhi(w1.w);
    }
    if (e < end) {
        uint4 w0 = tb[(long)adj[e] * 8 + p];
        a0 += bflo(w0.x); a1 += bfhi(w0.x);
        a2 += bflo(w0.y); a3 += bfhi(w0.y);
        a4 += bflo(w0.z); a5 += bfhi(w0.z);
        a6 += bflo(w0.w); a7 += bfhi(w0.w);
    }
    a0 += __shfl_xor(a0, 8);
    a1 += __shfl_xor(a1, 8);
    a2 += __shfl_xor(a2, 8);
    a3 += __shfl_xor(a3, 8);
    a4 += __shfl_xor(a4, 8);
    a5 += __shfl_xor(a5, 8);
    a6 += __shfl_xor(a6, 8);
    a7 += __shfl_xor(a7, 8);
    if (g == 0) {
        int cnt = end - beg;
        float inv = 1.f / (float)(cnt > 0 ? cnt : 1);
        const float4* bp = (const float4*)bias + 2 * p;
        float4 bv0 = bp[0], bv1 = bp[1];
        float4* op = (float4*)(out + (long)node * EMB) + 2 * p;
        float4 ov0 = op[0], ov1 = op[1];
        float4 o0, o1;
        o0.x = fmaxf(a0 * inv + bv0.x + ov0.x, 0.f);
        o0.y = fmaxf(a1 * inv + bv0.y + ov0.y, 0.f);
        o0.z = fmaxf(a2 * inv + bv0.z + ov0.z, 0.f);
        o0.w = fmaxf(a3 * inv + bv0.w + ov0.w, 0.f);
        o1.x = fmaxf(a4 * inv + bv1.x + ov1.x, 0.f);
        o1.y = fmaxf(a5 * inv + bv1.y + ov1.y, 0.f);
        o1.z = fmaxf(a6 * inv + bv1.z + ov1.z, 0.f);
        o1.w = fmaxf(a7 * inv + bv1.w + ov1.w, 0.f);
        op[0] = o0;
        op[1] = o1;
    }
}

extern "C" void kernel_launch(void* const* d_in, const int* in_sizes, int n_in,
                              void* d_out, int out_size, void* d_ws, size_t ws_size,
                              hipStream_t stream) {
    const float* cons_x     = (const float*)d_in[0];
    const float* var_x      = (const float*)d_in[1];
    const int*   eidx       = (const int*)d_in[3];
    const float* cons_shift = (const float*)d_in[4];
    const float* cons_scale = (const float*)d_in[5];
    const float* cons_w1    = (const float*)d_in[6];
    const float* cons_b1    = (const float*)d_in[7];
    const float* cons_w2    = (const float*)d_in[8];
    const float* cons_b2    = (const float*)d_in[9];
    const float* var_shift  = (const float*)d_in[10];
    const float* var_scale  = (const float*)d_in[11];
    const float* var_w1     = (const float*)d_in[12];
    const float* var_b1     = (const float*)d_in[13];
    const float* var_w2     = (const float*)d_in[14];
    const float* var_b2     = (const float*)d_in[15];
    const float* ll_w       = (const float*)d_in[18];
    const float* ll_b       = (const float*)d_in[19];
    const float* lr_w       = (const float*)d_in[20];

    const int nC = in_sizes[0] / 5;
    const int nV = in_sizes[1] / 19;
    const int E  = in_sizes[3] / 2;
    const int* src = eidx;       // constraint ids
    const int* dst = eidx + E;   // variable ids

    int shc = 0; while ((nC >> shc) >= 512) ++shc;
    int shv = 0; while ((nV >> shv) >= 512) ++shv;
    const int NBC = (nC + (1 << shc) - 1) >> shc;
    const int NBV = (nV + (1 << shv) - 1) >> shv;

    char* w = (char*)d_ws;
    auto alloc = [&](size_t bytes) {
        char* p = w;
        w += (bytes + 255) & ~(size_t)255;
        return p;
    };
    float* x_c = (float*)alloc((size_t)nC * EMB * 4);   // u_c, then xhat_c
    float* x_v = (float*)alloc((size_t)nV * EMB * 4);   // u_v, then xhat_v
    float* t_c = (float*)alloc((size_t)nC * EMB * 4);   // aliases: slotted tmp_c, then bf16 tb_c
    float* t_v = (float*)alloc((size_t)nV * EMB * 4);
    unsigned* tmp_c = (unsigned*)t_c;
    unsigned* tmp_v = (unsigned*)t_v;
    unsigned short* tb_c = (unsigned short*)t_c;
    unsigned short* tb_v = (unsigned short*)t_v;
    int* rp_v  = (int*)alloc((size_t)(nV + 1) * 4);
    int* rp_c  = (int*)alloc((size_t)(nC + 1) * 4);
    int* adj_v = (int*)alloc((size_t)E * 4);
    int* adj_c = (int*)alloc((size_t)E * 4);
    int* bkt   = (int*)alloc(2048 * 4);
    int* gcur_c = bkt;            // counts, then exclusive bases (NBC+1)
    int* gcur_v = bkt + 1024;     // counts, then exclusive bases (NBV+1)

    // fixed per-bucket slots in tmp (2x mean, clamped to region capacity)
    auto slot_for = [&](int NB, size_t cap_ints) {
        long s = 2L * E / NB;
        s = (s + 255) & ~255L;
        if (s < 4096) s = 4096;
        long cap = (long)(cap_ints / NB) & ~255L;
        if (s > cap) s = cap;
        return (int)s;
    };
    const int SLOTC = slot_for(NBC, (size_t)nC * EMB);
    const int SLOTV = slot_for(NBV, (size_t)nV * EMB);

    auto llw = [&](int l, int d) { return ll_w + (size_t)(l * 2 + d) * EMB * EMB; };
    auto lrw = [&](int l, int d) { return lr_w + (size_t)(l * 2 + d) * EMB * EMB; };
    auto llb = [&](int l, int d) { return ll_b + (size_t)(l * 2 + d) * EMB; };

    // ---- CSR build (no histogram pass: fixed slots + post-scan) ----
    zero_int_kernel<<<8, 256, 0, stream>>>(bkt, 2048);
    bin_edges_kernel<<<(E + CH - 1) / CH, 256, 0, stream>>>(src, dst, E, gcur_c, gcur_v,
                                                            tmp_c, tmp_v, shc, shv, NBC, NBV,
                                                            SLOTC, SLOTV);
    scan_buckets_kernel<<<1, 256, 0, stream>>>(gcur_c, NBC, gcur_v, NBV, E);
    regroup2_dual_kernel<<<NBV + NBC, 256, 0, stream>>>(
        tmp_v, gcur_v, rp_v, adj_v, nV, shv, NBV, SLOTV,
        tmp_c, gcur_c, rp_c, adj_c, nC, shc, NBC, SLOTC, E);

    // ---- fused embed + layer-0 GEMMs, both sides in one dispatch ----
    int gc = (nC + 63) / 64, gv = (nV + 63) / 64;
    embed_dual_kernel<5, 19><<<gc + gv, 256, 0, stream>>>(
        cons_x, cons_shift, cons_scale, cons_w1, cons_b1, cons_w2, cons_b2,
        llw(0, 0), lrw(0, 1), tb_c, x_c, nC,
        var_x, var_shift, var_scale, var_w1, var_b1, var_w2, var_b2,
        llw(0, 1), lrw(0, 0), tb_v, x_v, nV,
        gc);

    // ---- layer-0 aggs (RMW u -> xhat), SEQUENTIAL (L2 working-set) ----
    int gv16 = (nV + 15) / 16, gc16 = (nC + 15) / 16;
    agg_rmw_kernel<<<gv16, 256, 0, stream>>>(tb_c, rp_v, adj_v, llb(0, 0), x_v, nV);
    agg_rmw_kernel<<<gc16, 256, 0, stream>>>(tb_v, rp_c, adj_c, llb(0, 1), x_c, nC);

    // ---- layer-1 GEMMs, one dispatch ----
    gemm64_dual_kernel<<<gc + gv, 256, 0, stream>>>(
        x_c, nC, llw(1, 0), tb_c,
        x_v, nV, lrw(1, 0), (float*)d_out, gc);

    // ---- final layer-1 var agg (RMW d_out) ----
    agg_rmw_kernel<<<gv16, 256, 0, stream>>>(tb_c, rp_v, adj_v, llb(1, 0), (float*)d_out, nV);
}